// Round 1
// baseline (49.412 us; speedup 1.0000x reference)
//
#include <hip/hip_runtime.h>

// Shapes (compile-time constants from the reference)
#define BQ 4     // B
#define VV 384   // V visible nodes
#define HH 128   // H hidden nodes
#define NN 512   // N = V + H
#define HDIM 64  // HD
#define TD 128   // T*D

// K1: per-row pipeline. One wave (64 lanes) per (b, j) row, j in [0, N).
// visible rows: x -> relu(x@w_in1+b1) -> relu(@w_in2+b2) -> bb = h@w_e1[HD:]
// all rows:     E2 = relu(relu(bb + b_e1) @ w_e2 + b_e2)
__global__ __launch_bounds__(256) void k_rowpipe(
    const float* __restrict__ x,       // (B,V,128)
    const float* __restrict__ w_in1,   // (128,64)
    const float* __restrict__ b_in1,   // (64)
    const float* __restrict__ w_in2,   // (64,64)
    const float* __restrict__ b_in2,   // (64)
    const float* __restrict__ w_e1,    // (128,64) ; rows [64:128) are the sender half
    const float* __restrict__ b_e1,    // (64)
    const float* __restrict__ w_e2,    // (64,64)
    const float* __restrict__ b_e2,    // (64)
    float* __restrict__ E2)            // (B,N,64) in workspace
{
    const int wave = (blockIdx.x * blockDim.x + threadIdx.x) >> 6;
    const int lane = threadIdx.x & 63;
    if (wave >= BQ * NN) return;
    const int b = wave / NN;
    const int j = wave % NN;

    float bbv = 0.f;
    if (j < VV) {  // wave-uniform branch (one row per wave)
        const float* xr = x + (size_t)(b * VV + j) * TD;
        float acc = b_in1[lane];
        #pragma unroll 8
        for (int k = 0; k < TD; ++k)
            acc = fmaf(xr[k], w_in1[k * HDIM + lane], acc);
        const float h1 = fmaxf(acc, 0.f);

        acc = b_in2[lane];
        #pragma unroll 8
        for (int k = 0; k < HDIM; ++k)
            acc = fmaf(__shfl(h1, k, 64), w_in2[k * HDIM + lane], acc);
        const float h2 = fmaxf(acc, 0.f);

        acc = 0.f;
        #pragma unroll 8
        for (int k = 0; k < HDIM; ++k)
            acc = fmaf(__shfl(h2, k, 64), w_e1[(HDIM + k) * HDIM + lane], acc);
        bbv = acc;
    }

    const float e1 = fmaxf(bbv + b_e1[lane], 0.f);
    float acc = b_e2[lane];
    #pragma unroll 8
    for (int k = 0; k < HDIM; ++k)
        acc = fmaf(__shfl(e1, k, 64), w_e2[k * HDIM + lane], acc);
    E2[(size_t)wave * HDIM + lane] = fmaxf(acc, 0.f);
}

// K2: one wave per hidden receiver row (b, i=V+hi), 512 waves total.
// agg = adj[b,i,:] @ E2[b]  ->  node MLP  ->  out row (128 cols, 2/lane)
__global__ __launch_bounds__(256) void k_agg_out(
    const float* __restrict__ adj,   // (B,N,N)
    const float* __restrict__ E2,    // (B,N,64)
    const float* __restrict__ w_n1, const float* __restrict__ b_n1,
    const float* __restrict__ w_n2, const float* __restrict__ b_n2,
    const float* __restrict__ w_out, // (64,128)
    const float* __restrict__ b_out, // (128)
    float* __restrict__ out)         // (B,H,128)
{
    const int wave = (blockIdx.x * blockDim.x + threadIdx.x) >> 6;
    const int lane = threadIdx.x & 63;
    if (wave >= BQ * HH) return;
    const int b = wave / HH;
    const int hi = wave % HH;
    const int i = VV + hi;

    const float* adjrow = adj + ((size_t)b * NN + i) * NN;
    const float* e2b    = E2 + (size_t)b * NN * HDIM;

    float acc = 0.f;
    #pragma unroll 4
    for (int j = 0; j < NN; ++j)
        acc = fmaf(adjrow[j], e2b[j * HDIM + lane], acc);

    float t = b_n1[lane];
    #pragma unroll 8
    for (int k = 0; k < HDIM; ++k)
        t = fmaf(__shfl(acc, k, 64), w_n1[k * HDIM + lane], t);
    const float n1 = fmaxf(t, 0.f);

    t = b_n2[lane];
    #pragma unroll 8
    for (int k = 0; k < HDIM; ++k)
        t = fmaf(__shfl(n1, k, 64), w_n2[k * HDIM + lane], t);
    const float n2 = fmaxf(t, 0.f);

    float o0 = b_out[lane];
    float o1 = b_out[64 + lane];
    #pragma unroll 8
    for (int k = 0; k < HDIM; ++k) {
        const float v = __shfl(n2, k, 64);
        o0 = fmaf(v, w_out[k * TD + lane], o0);
        o1 = fmaf(v, w_out[k * TD + 64 + lane], o1);
    }
    float* orow = out + (size_t)wave * TD;
    orow[lane]      = o0;
    orow[64 + lane] = o1;
}

extern "C" void kernel_launch(void* const* d_in, const int* in_sizes, int n_in,
                              void* d_out, int out_size, void* d_ws, size_t ws_size,
                              hipStream_t stream) {
    const float* x     = (const float*)d_in[0];
    const float* adj   = (const float*)d_in[1];
    const float* w_in1 = (const float*)d_in[2];
    const float* b_in1 = (const float*)d_in[3];
    const float* w_in2 = (const float*)d_in[4];
    const float* b_in2 = (const float*)d_in[5];
    const float* w_e1  = (const float*)d_in[6];
    const float* b_e1  = (const float*)d_in[7];
    const float* w_e2  = (const float*)d_in[8];
    const float* b_e2  = (const float*)d_in[9];
    const float* w_n1  = (const float*)d_in[10];
    const float* b_n1  = (const float*)d_in[11];
    const float* w_n2  = (const float*)d_in[12];
    const float* b_n2  = (const float*)d_in[13];
    const float* w_out = (const float*)d_in[14];
    const float* b_out = (const float*)d_in[15];
    float* out = (float*)d_out;
    float* E2  = (float*)d_ws;   // B*N*64 floats = 512 KiB

    // K1: B*N = 2048 waves -> 512 blocks of 256 threads
    k_rowpipe<<<(BQ * NN * 64) / 256, 256, 0, stream>>>(
        x, w_in1, b_in1, w_in2, b_in2, w_e1, b_e1, w_e2, b_e2, E2);
    // K2: B*H = 512 waves -> 128 blocks of 256 threads
    k_agg_out<<<(BQ * HH * 64) / 256, 256, 0, stream>>>(
        adj, E2, w_n1, b_n1, w_n2, b_n2, w_out, b_out, out);
}

// Round 2
// 22.759 us; speedup vs baseline: 2.1711x; 2.1711x over previous
//
#include <hip/hip_runtime.h>

// Shapes (compile-time constants from the reference)
#define BQ 4     // B
#define VV 384   // V visible nodes
#define HH 128   // H hidden nodes
#define NN 512   // N = V + H
#define HDIM 64  // HD
#define TD 128   // T*D

// K1: per-row pipeline. One wave (64 lanes) per (b, j) row, j in [0, N).
// visible rows: x -> relu(x@w_in1+b1) -> relu(@w_in2+b2) -> bb = h@w_e1[HD:]
// all rows:     E2 = relu(relu(bb + b_e1) @ w_e2 + b_e2)
__global__ __launch_bounds__(256) void k_rowpipe(
    const float* __restrict__ x,       // (B,V,128)
    const float* __restrict__ w_in1,   // (128,64)
    const float* __restrict__ b_in1,   // (64)
    const float* __restrict__ w_in2,   // (64,64)
    const float* __restrict__ b_in2,   // (64)
    const float* __restrict__ w_e1,    // (128,64) ; rows [64:128) = sender half
    const float* __restrict__ b_e1,    // (64)
    const float* __restrict__ w_e2,    // (64,64)
    const float* __restrict__ b_e2,    // (64)
    float* __restrict__ E2)            // (B,N,64) in workspace
{
    const int wave = (blockIdx.x * blockDim.x + threadIdx.x) >> 6;
    const int lane = threadIdx.x & 63;
    if (wave >= BQ * NN) return;
    const int b = wave / NN;
    const int j = wave % NN;

    float bbv = 0.f;
    if (j < VV) {  // wave-uniform branch (one row per wave)
        const float* xr = x + (size_t)(b * VV + j) * TD;
        // coalesced load of the x row, then shfl-broadcast (no uniform loads)
        const float xv0 = xr[lane];
        const float xv1 = xr[64 + lane];

        float a0 = b_in1[lane], a1 = 0.f;
        #pragma unroll 8
        for (int k = 0; k < HDIM; ++k) {
            a0 = fmaf(__shfl(xv0, k, 64), w_in1[k * HDIM + lane], a0);
            a1 = fmaf(__shfl(xv1, k, 64), w_in1[(HDIM + k) * HDIM + lane], a1);
        }
        const float h1 = fmaxf(a0 + a1, 0.f);

        a0 = b_in2[lane]; a1 = 0.f;
        #pragma unroll 8
        for (int k = 0; k < HDIM; k += 2) {
            a0 = fmaf(__shfl(h1, k, 64),     w_in2[k * HDIM + lane],       a0);
            a1 = fmaf(__shfl(h1, k + 1, 64), w_in2[(k + 1) * HDIM + lane], a1);
        }
        const float h2 = fmaxf(a0 + a1, 0.f);

        a0 = 0.f; a1 = 0.f;
        #pragma unroll 8
        for (int k = 0; k < HDIM; k += 2) {
            a0 = fmaf(__shfl(h2, k, 64),     w_e1[(HDIM + k) * HDIM + lane],     a0);
            a1 = fmaf(__shfl(h2, k + 1, 64), w_e1[(HDIM + k + 1) * HDIM + lane], a1);
        }
        bbv = a0 + a1;
    }

    const float e1 = fmaxf(bbv + b_e1[lane], 0.f);
    float a0 = b_e2[lane], a1 = 0.f;
    #pragma unroll 8
    for (int k = 0; k < HDIM; k += 2) {
        a0 = fmaf(__shfl(e1, k, 64),     w_e2[k * HDIM + lane],       a0);
        a1 = fmaf(__shfl(e1, k + 1, 64), w_e2[(k + 1) * HDIM + lane], a1);
    }
    E2[(size_t)wave * HDIM + lane] = fmaxf(a0 + a1, 0.f);
}

// K2: one block (8 waves, 512 threads) per hidden receiver row (b, i=V+hi).
// wave w sums j in [64w, 64w+64); LDS-reduce; wave 0 does node MLP + out.
__global__ __launch_bounds__(512) void k_agg_out(
    const float* __restrict__ adj,   // (B,N,N)
    const float* __restrict__ E2,    // (B,N,64)
    const float* __restrict__ w_n1, const float* __restrict__ b_n1,
    const float* __restrict__ w_n2, const float* __restrict__ b_n2,
    const float* __restrict__ w_out, // (64,128)
    const float* __restrict__ b_out, // (128)
    float* __restrict__ out)         // (B,H,128)
{
    const int row  = blockIdx.x;          // 0 .. B*H-1
    const int b    = row / HH;
    const int hi   = row % HH;
    const int i    = VV + hi;
    const int wid  = threadIdx.x >> 6;    // 0..7
    const int lane = threadIdx.x & 63;

    const float* adjrow = adj + ((size_t)b * NN + i) * NN;
    const float* e2b    = E2 + ((size_t)b * NN + wid * 64) * HDIM;

    // coalesced load of this wave's 64 adj weights, then shfl-broadcast
    const float adjv = adjrow[wid * 64 + lane];

    float acc = 0.f;
    #pragma unroll 8
    for (int jj = 0; jj < 64; ++jj)
        acc = fmaf(__shfl(adjv, jj, 64), e2b[jj * HDIM + lane], acc);

    __shared__ float red[8][HDIM];
    red[wid][lane] = acc;
    __syncthreads();
    if (wid != 0) return;

    acc = (red[0][lane] + red[1][lane]) + (red[2][lane] + red[3][lane])
        + ((red[4][lane] + red[5][lane]) + (red[6][lane] + red[7][lane]));

    float t0 = b_n1[lane], t1 = 0.f;
    #pragma unroll 8
    for (int k = 0; k < HDIM; k += 2) {
        t0 = fmaf(__shfl(acc, k, 64),     w_n1[k * HDIM + lane],       t0);
        t1 = fmaf(__shfl(acc, k + 1, 64), w_n1[(k + 1) * HDIM + lane], t1);
    }
    const float n1 = fmaxf(t0 + t1, 0.f);

    t0 = b_n2[lane]; t1 = 0.f;
    #pragma unroll 8
    for (int k = 0; k < HDIM; k += 2) {
        t0 = fmaf(__shfl(n1, k, 64),     w_n2[k * HDIM + lane],       t0);
        t1 = fmaf(__shfl(n1, k + 1, 64), w_n2[(k + 1) * HDIM + lane], t1);
    }
    const float n2 = fmaxf(t0 + t1, 0.f);

    float o0 = b_out[lane];
    float o1 = b_out[64 + lane];
    #pragma unroll 8
    for (int k = 0; k < HDIM; ++k) {
        const float v = __shfl(n2, k, 64);
        o0 = fmaf(v, w_out[k * TD + lane], o0);
        o1 = fmaf(v, w_out[k * TD + 64 + lane], o1);
    }
    float* orow = out + (size_t)row * TD;
    orow[lane]      = o0;
    orow[64 + lane] = o1;
}

extern "C" void kernel_launch(void* const* d_in, const int* in_sizes, int n_in,
                              void* d_out, int out_size, void* d_ws, size_t ws_size,
                              hipStream_t stream) {
    const float* x     = (const float*)d_in[0];
    const float* adj   = (const float*)d_in[1];
    const float* w_in1 = (const float*)d_in[2];
    const float* b_in1 = (const float*)d_in[3];
    const float* w_in2 = (const float*)d_in[4];
    const float* b_in2 = (const float*)d_in[5];
    const float* w_e1  = (const float*)d_in[6];
    const float* b_e1  = (const float*)d_in[7];
    const float* w_e2  = (const float*)d_in[8];
    const float* b_e2  = (const float*)d_in[9];
    const float* w_n1  = (const float*)d_in[10];
    const float* b_n1  = (const float*)d_in[11];
    const float* w_n2  = (const float*)d_in[12];
    const float* b_n2  = (const float*)d_in[13];
    const float* w_out = (const float*)d_in[14];
    const float* b_out = (const float*)d_in[15];
    float* out = (float*)d_out;
    float* E2  = (float*)d_ws;   // B*N*64 floats = 512 KiB

    // K1: B*N = 2048 waves -> 512 blocks of 256 threads
    k_rowpipe<<<(BQ * NN * 64) / 256, 256, 0, stream>>>(
        x, w_in1, b_in1, w_in2, b_in2, w_e1, b_e1, w_e2, b_e2, E2);
    // K2: one 512-thread block per hidden row -> B*H = 512 blocks
    k_agg_out<<<BQ * HH, 512, 0, stream>>>(
        adj, E2, w_n1, b_n1, w_n2, b_n2, w_out, b_out, out);
}